// Round 3
// baseline (66.787 us; speedup 1.0000x reference)
//
#include <hip/hip_runtime.h>
#include <math.h>

#define STEPS 4096
#define BLOCK 512
#define PER_THREAD (STEPS / BLOCK)   // 8
#define NWAVES (BLOCK / 64)          // 8

// EKF loss. Structural reduction:
//  - P remains block-diagonal (cross block exactly 0), K rows 2..4 are 0,
//    so states 2..4 never influence preds; preds = X[:2] post-update.
//  - With diagonal R and P0=100*I, the observed 2x2 covariance block stays
//    diagonal; each axis follows a scalar Riccati  a'=a+q; a=r*a'/(a'+r),
//    a constant Mobius map -> closed form per step (per axis).
//  - preds p_t = (1-k_t) p_{t-1} + k_t z_t : affine prefix scan, p_{-1}=X0[:2].
__global__ __launch_bounds__(BLOCK) void ekf_loss_kernel(
    const float* __restrict__ meas,    // (STEPS,2)
    const float* __restrict__ truep,   // (STEPS,2)
    const float* __restrict__ X0,      // (5,1)
    const float* __restrict__ Qm,      // (1,)
    const float* __restrict__ Rm,      // (2,2)
    float* __restrict__ out)           // (1,)
{
    const int tid = threadIdx.x;
    const int base = tid * PER_THREAD;

    // ---- closed-form scalar Riccati constants (double), per axis ----
    const double q  = (double)Qm[0];
    const double rx = (double)Rm[0];   // R[0][0]
    const double ry = (double)Rm[3];   // R[1][1]

    // axis x
    const double discx = sqrt(q * q + 4.0 * q * rx);
    const double fppx = 0.5 * (q + discx);
    const double fmmx = 0.5 * (q - discx);
    const double a0p = 100.0 + q;                       // a'_0 (P0 = 100*I)
    const double w0x = (a0p - fppx) / (a0p - fmmx);
    const double l2rx = log2((fmmx + rx) / (fppx + rx));
    // axis y
    const double discy = sqrt(q * q + 4.0 * q * ry);
    const double fppy = 0.5 * (q + discy);
    const double fmmy = 0.5 * (q - discy);
    const double w0y = (a0p - fppy) / (a0p - fmmy);
    const double l2ry = log2((fmmy + ry) / (fppy + ry));

    // ---- per-element affine coefficients + local (serial) composition ----
    // p_t = m_t * p_{t-1} + b_t,  m_t = 1-k_t, b_t = k_t*z_t  (per axis)
    double mxs[PER_THREAD], mys[PER_THREAD], bxs[PER_THREAD], bys[PER_THREAD];
    double cmx = 1.0, cmy = 1.0, cbx = 0.0, cby = 0.0;
#pragma unroll
    for (int i = 0; i < PER_THREAD; ++i) {
        const int s = base + i;
        const double wx = w0x * exp2((double)s * l2rx);
        const double apx = (fppx - wx * fmmx) / (1.0 - wx);
        const double kx = apx / (apx + rx);
        const double wy = w0y * exp2((double)s * l2ry);
        const double apy = (fppy - wy * fmmy) / (1.0 - wy);
        const double ky = apy / (apy + ry);
        const double zx = (double)meas[2 * s + 0];
        const double zy = (double)meas[2 * s + 1];
        mxs[i] = 1.0 - kx;
        mys[i] = 1.0 - ky;
        bxs[i] = kx * zx;
        bys[i] = ky * zy;
        // compose (current = element_i o running)
        cbx = mxs[i] * cbx + bxs[i];
        cby = mys[i] * cby + bys[i];
        cmx = mxs[i] * cmx;
        cmy = mys[i] * cmy;
    }

    // ---- block-wide Hillis-Steele inclusive scan of affine pairs ----
    __shared__ double smx[BLOCK], smy[BLOCK], sbx[BLOCK], sby[BLOCK];
    smx[tid] = cmx; smy[tid] = cmy; sbx[tid] = cbx; sby[tid] = cby;
    __syncthreads();
    for (int off = 1; off < BLOCK; off <<= 1) {
        double pmx = 1.0, pmy = 1.0, pbx = 0.0, pby = 0.0;
        const bool has = (tid >= off);
        if (has) {
            pmx = smx[tid - off]; pmy = smy[tid - off];
            pbx = sbx[tid - off]; pby = sby[tid - off];
        }
        __syncthreads();
        if (has) {
            // compose(current o earlier): m = cm*pm, b = cm*pb + cb
            cbx = cmx * pbx + cbx;
            cby = cmy * pby + cby;
            cmx = cmx * pmx;
            cmy = cmy * pmy;
            smx[tid] = cmx; smy[tid] = cmy; sbx[tid] = cbx; sby[tid] = cby;
        }
        __syncthreads();
    }

    // ---- exclusive prefix -> starting p for this thread's chunk ----
    const double x0 = (double)X0[0];
    const double y0 = (double)X0[1];
    double px, py;
    if (tid == 0) { px = x0; py = y0; }
    else {
        px = smx[tid - 1] * x0 + sbx[tid - 1];
        py = smy[tid - 1] * y0 + sby[tid - 1];
    }

    // ---- replay chunk, accumulate squared error ----
    double acc = 0.0;
#pragma unroll
    for (int i = 0; i < PER_THREAD; ++i) {
        const int s = base + i;
        px = mxs[i] * px + bxs[i];
        py = mys[i] * py + bys[i];
        const double dx = px - (double)truep[2 * s + 0];
        const double dy = py - (double)truep[2 * s + 1];
        acc += dx * dx + dy * dy;
    }

    // ---- block reduction (wave shuffle + LDS) ----
#pragma unroll
    for (int off = 32; off > 0; off >>= 1)
        acc += __shfl_down(acc, off, 64);
    __shared__ double wacc[NWAVES];
    if ((tid & 63) == 0) wacc[tid >> 6] = acc;
    __syncthreads();
    if (tid == 0) {
        double tot = 0.0;
#pragma unroll
        for (int w = 0; w < NWAVES; ++w) tot += wacc[w];
        out[0] = (float)(tot / (double)(2 * STEPS));
    }
}

extern "C" void kernel_launch(void* const* d_in, const int* in_sizes, int n_in,
                              void* d_out, int out_size, void* d_ws, size_t ws_size,
                              hipStream_t stream) {
    const float* meas  = (const float*)d_in[0];
    const float* truep = (const float*)d_in[1];
    const float* X0    = (const float*)d_in[2];
    const float* Qm    = (const float*)d_in[3];
    const float* Rm    = (const float*)d_in[4];
    float* out = (float*)d_out;
    ekf_loss_kernel<<<1, BLOCK, 0, stream>>>(meas, truep, X0, Qm, Rm, out);
}

// Round 4
// 62.729 us; speedup vs baseline: 1.0647x; 1.0647x over previous
//
#include <hip/hip_runtime.h>
#include <math.h>

#define STEPS 4096
#define BLOCK 512
#define PER_THREAD (STEPS / BLOCK)   // 8
#define HALF_PT (PER_THREAD / 2)     // 4 float4s (2 steps each)
#define NWAVES (BLOCK / 64)          // 8

// EKF loss, closed-form reduction (see round-0 analysis):
//  - P stays block-diagonal; K rows 2..4 == 0; preds = X[:2] post-update.
//  - Diagonal R => observed 2x2 covariance stays diagonal; per-axis scalar
//    Riccati a'=a+q, a=r*a'/(a'+r) is a constant Mobius map -> closed form:
//    with f+- = (q +- sqrt(q^2+4qr))/2, rho=(f-+r)/(f++r), w_t = w0*rho^t:
//    a'_t = (f+ - w_t f-)/(1-w_t);  k_t = N/D, m_t = 1-k_t = r(1-w_t)/D
//    where N = f+ - w f-, D = (f+ + r) - w (f- + r).   (m+k == 1 exactly)
//  - p_t = m_t p_{t-1} + k_t z_t : affine prefix scan; p_{-1} = X0[:2].
// All per-element math fp32 (tolerance ~0.5 absolute; fp32 error ~1e-4).
__global__ __launch_bounds__(BLOCK) void ekf_loss_kernel(
    const float* __restrict__ meas,    // (STEPS,2)
    const float* __restrict__ truep,   // (STEPS,2)
    const float* __restrict__ X0,      // (5,1)
    const float* __restrict__ Qm,      // (1,)
    const float* __restrict__ Rm,      // (2,2)
    float* __restrict__ out)           // (1,)
{
    const int tid  = threadIdx.x;
    const int lane = tid & 63;
    const int wave = tid >> 6;
    const int base = tid * PER_THREAD;

    // ---- setup constants in f64 (once), exported to f32 ----
    const double q  = (double)Qm[0];
    const double rx = (double)Rm[0];   // R[0][0]
    const double ry = (double)Rm[3];   // R[1][1]
    const double a0p = 100.0 + q;      // a'_0 (P0 = 100*I)

    const double discx = sqrt(q*q + 4.0*q*rx);
    const double fppx_d = 0.5*(q + discx), fmmx_d = 0.5*(q - discx);
    const float w0x  = (float)((a0p - fppx_d) / (a0p - fmmx_d));
    const float l2rx = (float)log2((fmmx_d + rx) / (fppx_d + rx));
    const float fppx = (float)fppx_d, fmmx = (float)fmmx_d;
    const float frx  = (float)(fppx_d + rx), fmrx = (float)(fmmx_d + rx);
    const float rxf  = (float)rx;

    const double discy = sqrt(q*q + 4.0*q*ry);
    const double fppy_d = 0.5*(q + discy), fmmy_d = 0.5*(q - discy);
    const float w0y  = (float)((a0p - fppy_d) / (a0p - fmmy_d));
    const float l2ry = (float)log2((fmmy_d + ry) / (fppy_d + ry));
    const float fppy = (float)fppy_d, fmmy = (float)fmmy_d;
    const float fry  = (float)(fppy_d + ry), fmry = (float)(fmmy_d + ry);
    const float ryf  = (float)ry;

    // ---- vectorized measurement loads (2 steps per float4) ----
    const float4* mz4 = reinterpret_cast<const float4*>(meas);
    float4 mv[HALF_PT];
#pragma unroll
    for (int j = 0; j < HALF_PT; ++j) mv[j] = mz4[tid * HALF_PT + j];

    // ---- per-element affine coeffs + local serial composition ----
    float mxs[PER_THREAD], mys[PER_THREAD], bxs[PER_THREAD], bys[PER_THREAD];
    float cmx = 1.0f, cmy = 1.0f, cbx = 0.0f, cby = 0.0f;
#pragma unroll
    for (int i = 0; i < PER_THREAD; ++i) {
        const int s = base + i;
        const float zx = (i & 1) ? mv[i >> 1].z : mv[i >> 1].x;
        const float zy = (i & 1) ? mv[i >> 1].w : mv[i >> 1].y;

        const float wx = w0x * exp2f((float)s * l2rx);
        const float Dx = frx - wx * fmrx;
        const float Nx = fppx - wx * fmmx;
        const float iDx = 1.0f / Dx;
        const float kx = Nx * iDx;
        const float mx = rxf * (1.0f - wx) * iDx;

        const float wy = w0y * exp2f((float)s * l2ry);
        const float Dy = fry - wy * fmry;
        const float Ny = fppy - wy * fmmy;
        const float iDy = 1.0f / Dy;
        const float ky = Ny * iDy;
        const float my = ryf * (1.0f - wy) * iDy;

        mxs[i] = mx; mys[i] = my;
        bxs[i] = kx * zx; bys[i] = ky * zy;
        // compose (element_i after running)
        cbx = mx * cbx + bxs[i];
        cby = my * cby + bys[i];
        cmx *= mx;
        cmy *= my;
    }

    // ---- wave-level inclusive affine scan (shfl, no barriers) ----
#pragma unroll
    for (int d = 1; d < 64; d <<= 1) {
        const float pmx = __shfl_up(cmx, d, 64);
        const float pbx = __shfl_up(cbx, d, 64);
        const float pmy = __shfl_up(cmy, d, 64);
        const float pby = __shfl_up(cby, d, 64);
        if (lane >= d) {
            cbx = cmx * pbx + cbx;
            cby = cmy * pby + cby;
            cmx *= pmx;
            cmy *= pmy;
        }
    }

    // ---- wave aggregates -> LDS ----
    __shared__ float wmx[NWAVES], wmy[NWAVES], wbx[NWAVES], wby[NWAVES];
    if (lane == 63) { wmx[wave] = cmx; wmy[wave] = cmy; wbx[wave] = cbx; wby[wave] = cby; }
    __syncthreads();

    // ---- exclusive prefix for this thread ----
    // lane-exclusive within wave
    float lmx = __shfl_up(cmx, 1, 64), lbx = __shfl_up(cbx, 1, 64);
    float lmy = __shfl_up(cmy, 1, 64), lby = __shfl_up(cby, 1, 64);
    if (lane == 0) { lmx = 1.0f; lbx = 0.0f; lmy = 1.0f; lby = 0.0f; }
    // wave-exclusive (compose aggregates of waves < mine, earliest first)
    float gmx = 1.0f, gbx = 0.0f, gmy = 1.0f, gby = 0.0f;
    for (int w = 0; w < wave; ++w) {
        gbx = wmx[w] * gbx + wbx[w];
        gby = wmy[w] * gby + wby[w];
        gmx *= wmx[w];
        gmy *= wmy[w];
    }
    // total exclusive: E = Lane_excl ∘ Wave_excl  (wave part applies first)
    const float emx = lmx * gmx, ebx = lmx * gbx + lbx;
    const float emy = lmy * gmy, eby = lmy * gby + lby;

    const float x0 = X0[0], y0 = X0[1];
    float px = emx * x0 + ebx;
    float py = emy * y0 + eby;

    // ---- replay chunk against true positions ----
    const float4* tp4 = reinterpret_cast<const float4*>(truep);
    float acc = 0.0f;
#pragma unroll
    for (int j = 0; j < HALF_PT; ++j) {
        const float4 tv = tp4[tid * HALF_PT + j];
        const int i0 = 2 * j, i1 = 2 * j + 1;
        px = mxs[i0] * px + bxs[i0];
        py = mys[i0] * py + bys[i0];
        float dx = px - tv.x, dy = py - tv.y;
        acc += dx * dx + dy * dy;
        px = mxs[i1] * px + bxs[i1];
        py = mys[i1] * py + bys[i1];
        dx = px - tv.z; dy = py - tv.w;
        acc += dx * dx + dy * dy;
    }

    // ---- block reduction ----
#pragma unroll
    for (int off = 32; off > 0; off >>= 1)
        acc += __shfl_down(acc, off, 64);
    __shared__ float wacc[NWAVES];
    if (lane == 0) wacc[wave] = acc;
    __syncthreads();
    if (tid == 0) {
        float tot = 0.0f;
#pragma unroll
        for (int w = 0; w < NWAVES; ++w) tot += wacc[w];
        out[0] = tot / (float)(2 * STEPS);
    }
}

extern "C" void kernel_launch(void* const* d_in, const int* in_sizes, int n_in,
                              void* d_out, int out_size, void* d_ws, size_t ws_size,
                              hipStream_t stream) {
    const float* meas  = (const float*)d_in[0];
    const float* truep = (const float*)d_in[1];
    const float* X0    = (const float*)d_in[2];
    const float* Qm    = (const float*)d_in[3];
    const float* Rm    = (const float*)d_in[4];
    float* out = (float*)d_out;
    ekf_loss_kernel<<<1, BLOCK, 0, stream>>>(meas, truep, X0, Qm, Rm, out);
}